// Round 16
// baseline (110.989 us; speedup 1.0000x reference)
//
#include <hip/hip_runtime.h>

typedef _Float16 half4 __attribute__((ext_vector_type(4)));
typedef _Float16 half8 __attribute__((ext_vector_type(8)));
typedef float    f32x4 __attribute__((ext_vector_type(4)));

#define MFMA16(a,b,c) __builtin_amdgcn_mfma_f32_16x16x16f16((a),(b),(c),0,0,0)
#define MFMA32(a,b,c) __builtin_amdgcn_mfma_f32_16x16x32_f16((a),(b),(c),0,0,0)

static constexpr int N_NODES  = 200000;
static constexpr int N_GRAPHS = 64;
static constexpr int SGPG     = 128;               // 32-node supergroups per graph
static constexpr int TOTAL_SG = N_GRAPHS * SGPG;   // 8192

// ---- workspace byte offsets ----
static constexpr size_t WS_ZWT    = 0;        // [64][128][16] f16 : (z@W1)^T per graph
static constexpr size_t WS_GSTART = 262144;   // 65 int
static constexpr size_t WS_IMG    = 263168;   // 37,888 B prefab LDS image
// image layout (byte-exact copy of main's LDS block):
//   [0,32768)      a2l : 2048 x half8 k-permuted W2T frags
//   [32768,36864)  a3l : 512 x half4 head frags
//   [36864,37376)  b1l : 128 f32   (kept for safety-net path)
//   [37376,37888)  b2l : 128 f32

// ---------------- prep: batch scan + zwt + LDS image (unchanged from r13) ----------------
__global__ __launch_bounds__(256) void gnn_prep(
    const int* __restrict__ batch,
    const float* __restrict__ z,
    const float* __restrict__ W1,
    const float* __restrict__ W2,
    const float* __restrict__ Wp,
    const float* __restrict__ Wv,
    const float* __restrict__ b1,
    const float* __restrict__ b2,
    int* __restrict__ gstart,
    _Float16* __restrict__ zwt,
    char* __restrict__ img)
{
    const int b = blockIdx.x, t = threadIdx.x;
    if (b < 782) {
        const int i = b * 256 + t;
        if (i < N_NODES) {
            const int bi   = batch[i];
            const int prev = (i == 0) ? -1 : batch[i - 1];
            if (bi != prev)
                for (int g = prev + 1; g <= bi; ++g) gstart[g] = i;
            if (i == N_NODES - 1)
                for (int g = bi + 1; g <= N_GRAPHS; ++g) gstart[g] = N_NODES;
        }
    } else if (b < 1294) {
        const int p = (b - 782) * 2 + (t >> 7);   // 0..1023 = (g,k)
        const int g = p >> 4, k = p & 15, d = t & 127;
        const float* zr = z + (g * 16 + k) * 128;
        float a0 = 0.f, a1 = 0.f, a2 = 0.f, a3 = 0.f;
#pragma unroll 8
        for (int c = 0; c < 128; c += 4) {
            a0 += zr[c    ] * W1[(c    ) * 128 + d];
            a1 += zr[c + 1] * W1[(c + 1) * 128 + d];
            a2 += zr[c + 2] * W1[(c + 2) * 128 + d];
            a3 += zr[c + 3] * W1[(c + 3) * 128 + d];
        }
        zwt[(g * 128 + d) * 16 + k] = (_Float16)((a0 + a1) + (a2 + a3));
    } else if (b < 1302) {
        const int e  = (b - 1294) * 256 + t;
        const int mo = e >> 8, tp = (e >> 6) & 3, ll = e & 63;
        const int nn = ll & 15, qq = ll >> 4;
        const int dcol = mo * 16 + nn;        // d_out
        const int c0   = tp * 32 + qq * 4;    // d_in base
        half8 v;
#pragma unroll
        for (int j = 0; j < 4; ++j) v[j]     = (_Float16)W2[(c0 + j) * 128 + dcol];
#pragma unroll
        for (int j = 0; j < 4; ++j) v[4 + j] = (_Float16)W2[(c0 + 16 + j) * 128 + dcol];
        *(half8*)(img + e * 16) = v;
    } else if (b < 1304) {
        const int ee = (b - 1302) * 256 + t;
        const int tt = ee >> 6, ll = ee & 63;
        const int nn = ll & 15, qq = ll >> 4;
        half4 v;
#pragma unroll
        for (int i = 0; i < 4; ++i) {
            const int d = tt * 16 + qq * 4 + i;
            float x = 0.f;
            if (nn < 2)      x = Wp[d * 2 + nn];
            else if (nn < 4) x = Wv[d * 2 + (nn - 2)];
            v[i] = (_Float16)x;
        }
        *(half4*)(img + 32768 + ee * 8) = v;
    } else {
        float* bi = (float*)(img + 36864);
        if (t < 128)      bi[t] = b1[t];
        else              bi[t] = b2[t - 128];
    }
}

__device__ inline float fast_tanh(float x) {
    x = fminf(fmaxf(x, -15.f), 15.f);
    const float e = __expf(2.f * x);
    return (e - 1.f) / (e + 1.f);
}

__device__ __forceinline__ half4 cvt4(f32x4 v) {
    half4 r;
    r[0] = (_Float16)v[0]; r[1] = (_Float16)v[1];
    r[2] = (_Float16)v[2]; r[3] = (_Float16)v[3];
    return r;
}

// predicated load of the two 16-node s-tiles for one supergroup (zeros past end)
__device__ __forceinline__ void load_s(const float* __restrict__ s,
                                       int base, int ge, int n16, int quad,
                                       f32x4& a, f32x4& b)
{
    const f32x4 z4 = {0.f, 0.f, 0.f, 0.f};
    a = z4; b = z4;
    if (base + n16 < ge)      a = *(const f32x4*)(s + (base + n16) * 16 + quad * 4);
    if (base + 16 + n16 < ge) b = *(const f32x4*)(s + (base + 16 + n16) * 16 + quad * 4);
}

// single-supergroup path (safety-net loop only; uses LDS biases)
__device__ __forceinline__ void compute_sg(
    int g, int base, int ge,
    half4 bsA, half4 bsB,
    const _Float16* __restrict__ zwt,
    const half8* a2l, const half4* a3l,
    const float* b1l, const float* b2l,
    f32x4 c3init, float* __restrict__ out,
    int lane, int n16, int quad)
{
    const int nodeA = base + n16;
    const int nodeB = base + 16 + n16;
    const bool vA = nodeA < ge;
    const bool vB = nodeB < ge;

    const _Float16* zg = zwt + g * 2048;
    half8 h1a8[4], h1b8[4];
#pragma unroll
    for (int mt = 0; mt < 8; ++mt) {
        const half4 a1 = *(const half4*)(zg + (mt * 16 + n16) * 16 + quad * 4);
        const f32x4 cb = *(const f32x4*)(b1l + mt * 16 + quad * 4);
        const f32x4 accA = MFMA16(a1, bsA, cb);
        const f32x4 accB = MFMA16(a1, bsB, cb);
        const int tp  = mt >> 1;
        const int off = (mt & 1) * 4;
#pragma unroll
        for (int i = 0; i < 4; ++i) {
            h1a8[tp][off + i] = (_Float16)fmaxf(accA[i], 0.f);
            h1b8[tp][off + i] = (_Float16)fmaxf(accB[i], 0.f);
        }
    }

    f32x4 acc3a = c3init, acc3b = c3init;
#pragma unroll
    for (int mo = 0; mo < 8; ++mo) {
        const f32x4 cb = *(const f32x4*)(b2l + mo * 16 + quad * 4);
        f32x4 a2a = cb, a2b = cb;
#pragma unroll
        for (int tp = 0; tp < 4; ++tp) {
            const half8 w = a2l[(mo * 4 + tp) * 64 + lane];
            a2a = MFMA32(w, h1a8[tp], a2a);
            a2b = MFMA32(w, h1b8[tp], a2b);
        }
        half4 h2a, h2b;
#pragma unroll
        for (int i = 0; i < 4; ++i) {
            h2a[i] = (_Float16)fmaxf(a2a[i], 0.f);
            h2b[i] = (_Float16)fmaxf(a2b[i], 0.f);
        }
        const half4 w3 = a3l[mo * 64 + lane];
        acc3a = MFMA16(w3, h2a, acc3a);
        acc3b = MFMA16(w3, h2b, acc3b);
    }

    if (quad == 0) {
        if (vA) {
            f32x4 o;
            o[0] = fast_tanh(acc3a[0]); o[1] = fast_tanh(acc3a[1]);
            o[2] = acc3a[2];            o[3] = acc3a[3];
            *(f32x4*)(out + nodeA * 4) = o;
        }
        if (vB) {
            f32x4 o;
            o[0] = fast_tanh(acc3b[0]); o[1] = fast_tanh(acc3b[1]);
            o[2] = acc3b[2];            o[3] = acc3b[3];
            *(f32x4*)(out + nodeB * 4) = o;
        }
    }
}

// ---------------- main ----------------
__global__ __launch_bounds__(256, 4) void gnn_main(
    const float* __restrict__ s,
    const float* __restrict__ b1,
    const float* __restrict__ b2,
    const float* __restrict__ bp,
    const float* __restrict__ bv,
    const _Float16* __restrict__ zwt,
    const char* __restrict__ img,
    const int* __restrict__ gstart,
    float* __restrict__ out)
{
    __shared__ char lds[37888];
    half8* a2l = (half8*)lds;                 // [mo*4+tp][lane] k-permuted W2T frags
    half4* a3l = (half4*)(lds + 32768);       // [t][lane] head weights
    float* b1l = (float*)(lds + 36864);       // safety-net path only
    float* b2l = (float*)(lds + 37376);

    const int tid  = threadIdx.x;
    const int lane = tid & 63;
    const int n16  = lane & 15;
    const int quad = lane >> 4;

    // ---- issue async staging (no wait yet): 37,888 B = 2368 x 16B ----
#pragma unroll
    for (int it = 0; it < 10; ++it) {
        const int idx = it * 256 + tid;       // 16B units
        if (idx < 2368) {
            __builtin_amdgcn_global_load_lds(
                (const __attribute__((address_space(1))) void*)(img + idx * 16),
                (__attribute__((address_space(3))) void*)(lds + (idx & ~63) * 16),
                16, 0, 0);
        }
    }

    const float bp0 = bp[0], bp1 = bp[1], bv0 = bv[0], bv1 = bv[1];
    f32x4 c3init = {0.f, 0.f, 0.f, 0.f};
    if (quad == 0) { c3init[0] = bp0; c3init[1] = bp1; c3init[2] = bv0; c3init[3] = bv1; }

    const int wid = blockIdx.x * 4 + (tid >> 6);
    const int nw  = gridDim.x * 4;            // 4096 at grid=1024

    const int sg0 = wid;
    const int sg1 = wid + nw;

    const int g0  = sg0 >> 7;
    const int gs0 = gstart[g0], ge0 = gstart[g0 + 1];
    const int base0 = gs0 + (sg0 & 127) * 32;
    const bool act0 = base0 < ge0;

    const bool in1 = sg1 < TOTAL_SG;
    const int g1  = in1 ? (sg1 >> 7) : 0;
    const int gs1 = in1 ? gstart[g1] : 0;
    const int ge1 = in1 ? gstart[g1 + 1] : 0;
    const int base1 = gs1 + (sg1 & 127) * 32;
    const bool act1 = in1 && (base1 < ge1);

    // T14: issue all s-tile loads up front (latency hides under staging+GEMM1)
    f32x4 sA0, sB0, sA1, sB1;
    const f32x4 z4 = {0.f, 0.f, 0.f, 0.f};
    sA0 = z4; sB0 = z4; sA1 = z4; sB1 = z4;
    if (act0) load_s(s, base0, ge0, n16, quad, sA0, sB0);
    if (act1) load_s(s, base1, ge1, n16, quad, sA1, sB1);

    const bool act = act0 || act1;

    // ---- GEMM1' BEFORE the barrier: all-global operands (zwt, s, b1) ----
    half8 h10a[4], h10b[4], h11a[4], h11b[4];
    half4 bs0A, bs0B, bs1A, bs1B;
    if (act) {
        bs0A = cvt4(sA0); bs0B = cvt4(sB0);
        bs1A = cvt4(sA1); bs1B = cvt4(sB1);
        const _Float16* zg0 = zwt + g0 * 2048;
        const _Float16* zg1 = zwt + g1 * 2048;
#pragma unroll
        for (int mt = 0; mt < 8; ++mt) {
            const half4 a10 = *(const half4*)(zg0 + (mt * 16 + n16) * 16 + quad * 4);
            const half4 a11 = *(const half4*)(zg1 + (mt * 16 + n16) * 16 + quad * 4);
            const f32x4 cb  = *(const f32x4*)(b1 + mt * 16 + quad * 4);  // global, L2-hot
            const f32x4 acc0A = MFMA16(a10, bs0A, cb);
            const f32x4 acc0B = MFMA16(a10, bs0B, cb);
            const f32x4 acc1A = MFMA16(a11, bs1A, cb);
            const f32x4 acc1B = MFMA16(a11, bs1B, cb);
            const int tp  = mt >> 1;
            const int off = (mt & 1) * 4;
#pragma unroll
            for (int i = 0; i < 4; ++i) {
                h10a[tp][off + i] = (_Float16)fmaxf(acc0A[i], 0.f);
                h10b[tp][off + i] = (_Float16)fmaxf(acc0B[i], 0.f);
                h11a[tp][off + i] = (_Float16)fmaxf(acc1A[i], 0.f);
                h11b[tp][off + i] = (_Float16)fmaxf(acc1B[i], 0.f);
            }
        }
    }

    // ---- drain staging + block barrier (reached by ALL threads exactly once) ----
    asm volatile("s_waitcnt vmcnt(0)");
    __syncthreads();

    if (act) {
        // ---- GEMM2' + head interleaved from LDS; 4 independent MFMA streams ----
        f32x4 acc3_0a = c3init, acc3_0b = c3init;
        f32x4 acc3_1a = c3init, acc3_1b = c3init;
        __builtin_amdgcn_s_setprio(1);
#pragma unroll
        for (int mo = 0; mo < 8; ++mo) {
            const f32x4 cb = *(const f32x4*)(b2 + mo * 16 + quad * 4);   // global, L2-hot
            f32x4 a0a = cb, a0b = cb, a1a = cb, a1b = cb;
#pragma unroll
            for (int tp = 0; tp < 4; ++tp) {
                const half8 w = a2l[(mo * 4 + tp) * 64 + lane];
                a0a = MFMA32(w, h10a[tp], a0a);
                a0b = MFMA32(w, h10b[tp], a0b);
                a1a = MFMA32(w, h11a[tp], a1a);
                a1b = MFMA32(w, h11b[tp], a1b);
            }
            half4 h20a, h20b, h21a, h21b;
#pragma unroll
            for (int i = 0; i < 4; ++i) {
                h20a[i] = (_Float16)fmaxf(a0a[i], 0.f);
                h20b[i] = (_Float16)fmaxf(a0b[i], 0.f);
                h21a[i] = (_Float16)fmaxf(a1a[i], 0.f);
                h21b[i] = (_Float16)fmaxf(a1b[i], 0.f);
            }
            const half4 w3 = a3l[mo * 64 + lane];
            acc3_0a = MFMA16(w3, h20a, acc3_0a);
            acc3_0b = MFMA16(w3, h20b, acc3_0b);
            acc3_1a = MFMA16(w3, h21a, acc3_1a);
            acc3_1b = MFMA16(w3, h21b, acc3_1b);
        }
        __builtin_amdgcn_s_setprio(0);

        if (quad == 0) {
            if (act0 && (base0 + n16 < ge0)) {
                f32x4 o;
                o[0] = fast_tanh(acc3_0a[0]); o[1] = fast_tanh(acc3_0a[1]);
                o[2] = acc3_0a[2];            o[3] = acc3_0a[3];
                *(f32x4*)(out + (base0 + n16) * 4) = o;
            }
            if (act0 && (base0 + 16 + n16 < ge0)) {
                f32x4 o;
                o[0] = fast_tanh(acc3_0b[0]); o[1] = fast_tanh(acc3_0b[1]);
                o[2] = acc3_0b[2];            o[3] = acc3_0b[3];
                *(f32x4*)(out + (base0 + 16 + n16) * 4) = o;
            }
            if (act1 && (base1 + n16 < ge1)) {
                f32x4 o;
                o[0] = fast_tanh(acc3_1a[0]); o[1] = fast_tanh(acc3_1a[1]);
                o[2] = acc3_1a[2];            o[3] = acc3_1a[3];
                *(f32x4*)(out + (base1 + n16) * 4) = o;
            }
            if (act1 && (base1 + 16 + n16 < ge1)) {
                f32x4 o;
                o[0] = fast_tanh(acc3_1b[0]); o[1] = fast_tanh(acc3_1b[1]);
                o[2] = acc3_1b[2];            o[3] = acc3_1b[3];
                *(f32x4*)(out + (base1 + 16 + n16) * 4) = o;
            }
        }
    }

    // safety net if grid ever shrinks below 1024 (zero iterations at grid=1024)
    for (int sgi = wid + 2 * nw; sgi < TOTAL_SG; sgi += nw) {
        const int g    = sgi >> 7;
        const int gs   = gstart[g];
        const int ge   = gstart[g + 1];
        const int base = gs + (sgi & 127) * 32;
        if (base >= ge) continue;
        f32x4 sa, sb;
        load_s(s, base, ge, n16, quad, sa, sb);
        compute_sg(g, base, ge, cvt4(sa), cvt4(sb),
                   zwt, a2l, a3l, b1l, b2l, c3init, out, lane, n16, quad);
    }
}

extern "C" void kernel_launch(void* const* d_in, const int* in_sizes, int n_in,
                              void* d_out, int out_size, void* d_ws, size_t ws_size,
                              hipStream_t stream)
{
    const float* z     = (const float*)d_in[0];
    const float* s     = (const float*)d_in[1];
    const int*   batch = (const int*)d_in[2];
    const float* W1    = (const float*)d_in[3];
    const float* b1    = (const float*)d_in[4];
    const float* W2    = (const float*)d_in[5];
    const float* b2    = (const float*)d_in[6];
    const float* Wp    = (const float*)d_in[7];
    const float* bp    = (const float*)d_in[8];
    const float* Wv    = (const float*)d_in[9];
    const float* bv    = (const float*)d_in[10];
    float* out = (float*)d_out;

    char* w = (char*)d_ws;
    _Float16* zwt = (_Float16*)(w + WS_ZWT);
    int* gstart   = (int*)(w + WS_GSTART);
    char* img     = w + WS_IMG;

    hipLaunchKernelGGL(gnn_prep, dim3(1305), dim3(256), 0, stream,
                       batch, z, W1, W2, Wp, Wv, b1, b2, gstart, zwt, img);
    hipLaunchKernelGGL(gnn_main, dim3(1024), dim3(256), 0, stream,
                       s, b1, b2, bp, bv, zwt, img, gstart, out);
}

// Round 17
// 102.075 us; speedup vs baseline: 1.0873x; 1.0873x over previous
//
#include <hip/hip_runtime.h>

typedef _Float16 half4 __attribute__((ext_vector_type(4)));
typedef _Float16 half8 __attribute__((ext_vector_type(8)));
typedef float    f32x4 __attribute__((ext_vector_type(4)));

#define MFMA16(a,b,c) __builtin_amdgcn_mfma_f32_16x16x16f16((a),(b),(c),0,0,0)
#define MFMA32(a,b,c) __builtin_amdgcn_mfma_f32_16x16x32_f16((a),(b),(c),0,0,0)

static constexpr int N_NODES  = 200000;
static constexpr int N_GRAPHS = 64;
static constexpr int SGPG     = 128;               // 32-node supergroups per graph
static constexpr int TOTAL_SG = N_GRAPHS * SGPG;   // 8192

// ---- workspace byte offsets ----
static constexpr size_t WS_ZWT    = 0;        // [64][128][16] f16 : (z@W1)^T per graph
static constexpr size_t WS_GSTART = 262144;   // 65 int
static constexpr size_t WS_IMG    = 263168;   // 37,888 B prefab LDS image
// image layout (byte-exact copy of main's LDS block):
//   [0,32768)      a2l : 2048 x half8 k-permuted W2T frags
//   [32768,36864)  a3l : 512 x half4 head frags
//   [36864,37376)  b1l : 128 f32
//   [37376,37888)  b2l : 128 f32

// ---------------- prep: batch scan + zwt + LDS image (r13-verified) ----------------
__global__ __launch_bounds__(256) void gnn_prep(
    const int* __restrict__ batch,
    const float* __restrict__ z,
    const float* __restrict__ W1,
    const float* __restrict__ W2,
    const float* __restrict__ Wp,
    const float* __restrict__ Wv,
    const float* __restrict__ b1,
    const float* __restrict__ b2,
    int* __restrict__ gstart,
    _Float16* __restrict__ zwt,
    char* __restrict__ img)
{
    const int b = blockIdx.x, t = threadIdx.x;
    if (b < 782) {
        const int i = b * 256 + t;
        if (i < N_NODES) {
            const int bi   = batch[i];
            const int prev = (i == 0) ? -1 : batch[i - 1];
            if (bi != prev)
                for (int g = prev + 1; g <= bi; ++g) gstart[g] = i;
            if (i == N_NODES - 1)
                for (int g = bi + 1; g <= N_GRAPHS; ++g) gstart[g] = N_NODES;
        }
    } else if (b < 1294) {
        const int p = (b - 782) * 2 + (t >> 7);   // 0..1023 = (g,k)
        const int g = p >> 4, k = p & 15, d = t & 127;
        const float* zr = z + (g * 16 + k) * 128;
        float a0 = 0.f, a1 = 0.f, a2 = 0.f, a3 = 0.f;
#pragma unroll 8
        for (int c = 0; c < 128; c += 4) {
            a0 += zr[c    ] * W1[(c    ) * 128 + d];
            a1 += zr[c + 1] * W1[(c + 1) * 128 + d];
            a2 += zr[c + 2] * W1[(c + 2) * 128 + d];
            a3 += zr[c + 3] * W1[(c + 3) * 128 + d];
        }
        zwt[(g * 128 + d) * 16 + k] = (_Float16)((a0 + a1) + (a2 + a3));
    } else if (b < 1302) {
        const int e  = (b - 1294) * 256 + t;
        const int mo = e >> 8, tp = (e >> 6) & 3, ll = e & 63;
        const int nn = ll & 15, qq = ll >> 4;
        const int dcol = mo * 16 + nn;        // d_out
        const int c0   = tp * 32 + qq * 4;    // d_in base
        half8 v;
#pragma unroll
        for (int j = 0; j < 4; ++j) v[j]     = (_Float16)W2[(c0 + j) * 128 + dcol];
#pragma unroll
        for (int j = 0; j < 4; ++j) v[4 + j] = (_Float16)W2[(c0 + 16 + j) * 128 + dcol];
        *(half8*)(img + e * 16) = v;
    } else if (b < 1304) {
        const int ee = (b - 1302) * 256 + t;
        const int tt = ee >> 6, ll = ee & 63;
        const int nn = ll & 15, qq = ll >> 4;
        half4 v;
#pragma unroll
        for (int i = 0; i < 4; ++i) {
            const int d = tt * 16 + qq * 4 + i;
            float x = 0.f;
            if (nn < 2)      x = Wp[d * 2 + nn];
            else if (nn < 4) x = Wv[d * 2 + (nn - 2)];
            v[i] = (_Float16)x;
        }
        *(half4*)(img + 32768 + ee * 8) = v;
    } else {
        float* bi = (float*)(img + 36864);
        if (t < 128)      bi[t] = b1[t];
        else              bi[t] = b2[t - 128];
    }
}

__device__ inline float fast_tanh(float x) {
    x = fminf(fmaxf(x, -15.f), 15.f);
    const float e = __expf(2.f * x);
    return (e - 1.f) / (e + 1.f);
}

__device__ __forceinline__ half4 cvt4(f32x4 v) {
    half4 r;
    r[0] = (_Float16)v[0]; r[1] = (_Float16)v[1];
    r[2] = (_Float16)v[2]; r[3] = (_Float16)v[3];
    return r;
}

// predicated load of the two 16-node s-tiles for one supergroup (zeros past end)
__device__ __forceinline__ void load_s(const float* __restrict__ s,
                                       int base, int ge, int n16, int quad,
                                       f32x4& a, f32x4& b)
{
    const f32x4 z4 = {0.f, 0.f, 0.f, 0.f};
    a = z4; b = z4;
    if (base + n16 < ge)      a = *(const f32x4*)(s + (base + n16) * 16 + quad * 4);
    if (base + 16 + n16 < ge) b = *(const f32x4*)(s + (base + 16 + n16) * 16 + quad * 4);
}

// single-supergroup path (safety-net loop only)
__device__ __forceinline__ void compute_sg(
    int g, int base, int ge,
    half4 bsA, half4 bsB,
    const _Float16* __restrict__ zwt,
    const half8* a2l, const half4* a3l,
    const float* b1l, const float* b2l,
    f32x4 c3init, float* __restrict__ out,
    int lane, int n16, int quad)
{
    const int nodeA = base + n16;
    const int nodeB = base + 16 + n16;
    const bool vA = nodeA < ge;
    const bool vB = nodeB < ge;

    const _Float16* zg = zwt + g * 2048;
    half8 h1a8[4], h1b8[4];
#pragma unroll
    for (int mt = 0; mt < 8; ++mt) {
        const half4 a1 = *(const half4*)(zg + (mt * 16 + n16) * 16 + quad * 4);
        const f32x4 cb = *(const f32x4*)(b1l + mt * 16 + quad * 4);
        const f32x4 accA = MFMA16(a1, bsA, cb);
        const f32x4 accB = MFMA16(a1, bsB, cb);
        const int tp  = mt >> 1;
        const int off = (mt & 1) * 4;
#pragma unroll
        for (int i = 0; i < 4; ++i) {
            h1a8[tp][off + i] = (_Float16)fmaxf(accA[i], 0.f);
            h1b8[tp][off + i] = (_Float16)fmaxf(accB[i], 0.f);
        }
    }

    f32x4 acc3a = c3init, acc3b = c3init;
#pragma unroll
    for (int mo = 0; mo < 8; ++mo) {
        const f32x4 cb = *(const f32x4*)(b2l + mo * 16 + quad * 4);
        f32x4 a2a = cb, a2b = cb;
#pragma unroll
        for (int tp = 0; tp < 4; ++tp) {
            const half8 w = a2l[(mo * 4 + tp) * 64 + lane];
            a2a = MFMA32(w, h1a8[tp], a2a);
            a2b = MFMA32(w, h1b8[tp], a2b);
        }
        half4 h2a, h2b;
#pragma unroll
        for (int i = 0; i < 4; ++i) {
            h2a[i] = (_Float16)fmaxf(a2a[i], 0.f);
            h2b[i] = (_Float16)fmaxf(a2b[i], 0.f);
        }
        const half4 w3 = a3l[mo * 64 + lane];
        acc3a = MFMA16(w3, h2a, acc3a);
        acc3b = MFMA16(w3, h2b, acc3b);
    }

    if (quad == 0) {
        if (vA) {
            f32x4 o;
            o[0] = fast_tanh(acc3a[0]); o[1] = fast_tanh(acc3a[1]);
            o[2] = acc3a[2];            o[3] = acc3a[3];
            *(f32x4*)(out + nodeA * 4) = o;
        }
        if (vB) {
            f32x4 o;
            o[0] = fast_tanh(acc3b[0]); o[1] = fast_tanh(acc3b[1]);
            o[2] = acc3b[2];            o[3] = acc3b[3];
            *(f32x4*)(out + nodeB * 4) = o;
        }
    }
}

// ---------------- main (r13 structure; gstart/s-loads hoisted before drain) ----------------
__global__ __launch_bounds__(256, 4) void gnn_main(
    const float* __restrict__ s,
    const float* __restrict__ bp,
    const float* __restrict__ bv,
    const _Float16* __restrict__ zwt,
    const char* __restrict__ img,
    const int* __restrict__ gstart,
    float* __restrict__ out)
{
    __shared__ char lds[37888];
    half8* a2l = (half8*)lds;                 // [mo*4+tp][lane] k-permuted W2T frags
    half4* a3l = (half4*)(lds + 32768);       // [t][lane] head weights
    float* b1l = (float*)(lds + 36864);
    float* b2l = (float*)(lds + 37376);

    const int tid  = threadIdx.x;
    const int lane = tid & 63;
    const int n16  = lane & 15;
    const int quad = lane >> 4;

    // ---- issue async staging: 37,888 B = 2368 x 16B via global_load_lds ----
#pragma unroll
    for (int it = 0; it < 10; ++it) {
        const int idx = it * 256 + tid;       // 16B units
        if (idx < 2368) {
            __builtin_amdgcn_global_load_lds(
                (const __attribute__((address_space(1))) void*)(img + idx * 16),
                (__attribute__((address_space(3))) void*)(lds + (idx & ~63) * 16),
                16, 0, 0);
        }
    }

    // ---- cheap hoists that overlap the staging drain (16 VGPRs + scalars) ----
    const float bp0 = bp[0], bp1 = bp[1], bv0 = bv[0], bv1 = bv[1];
    f32x4 c3init = {0.f, 0.f, 0.f, 0.f};
    if (quad == 0) { c3init[0] = bp0; c3init[1] = bp1; c3init[2] = bv0; c3init[3] = bv1; }

    const int wid = blockIdx.x * 4 + (tid >> 6);
    const int nw  = gridDim.x * 4;            // 4096 at grid=1024

    const int sg0 = wid;
    const int sg1 = wid + nw;

    const int g0  = sg0 >> 7;
    const int gs0 = gstart[g0], ge0 = gstart[g0 + 1];
    const int base0 = gs0 + (sg0 & 127) * 32;
    const bool act0 = base0 < ge0;

    const bool in1 = sg1 < TOTAL_SG;
    const int g1  = in1 ? (sg1 >> 7) : 0;
    const int gs1 = in1 ? gstart[g1] : 0;
    const int ge1 = in1 ? gstart[g1 + 1] : 0;
    const int base1 = gs1 + (sg1 & 127) * 32;
    const bool act1 = in1 && (base1 < ge1);

    // T14: issue s-tile loads before the drain; their HBM latency hides under it
    f32x4 sA0, sB0, sA1, sB1;
    const f32x4 z4 = {0.f, 0.f, 0.f, 0.f};
    sA0 = z4; sB0 = z4; sA1 = z4; sB1 = z4;
    if (act0) load_s(s, base0, ge0, n16, quad, sA0, sB0);
    if (act1) load_s(s, base1, ge1, n16, quad, sA1, sB1);

    // ---- drain staging (+ s-loads) and barrier ----
    asm volatile("s_waitcnt vmcnt(0)");
    __syncthreads();

    if (act0 || act1) {
        // ---- dual-supergroup interleaved compute: 4 independent MFMA streams ----
        const half4 bs0A = cvt4(sA0), bs0B = cvt4(sB0);
        const half4 bs1A = cvt4(sA1), bs1B = cvt4(sB1);
        const _Float16* zg0 = zwt + g0 * 2048;
        const _Float16* zg1 = zwt + g1 * 2048;

        // GEMM1' interleaved (bias via C-init), packed into K=32 B-frags
        half8 h10a[4], h10b[4], h11a[4], h11b[4];
#pragma unroll
        for (int mt = 0; mt < 8; ++mt) {
            const half4 a10 = *(const half4*)(zg0 + (mt * 16 + n16) * 16 + quad * 4);
            const half4 a11 = *(const half4*)(zg1 + (mt * 16 + n16) * 16 + quad * 4);
            const f32x4 cb  = *(const f32x4*)(b1l + mt * 16 + quad * 4);
            const f32x4 acc0A = MFMA16(a10, bs0A, cb);
            const f32x4 acc0B = MFMA16(a10, bs0B, cb);
            const f32x4 acc1A = MFMA16(a11, bs1A, cb);
            const f32x4 acc1B = MFMA16(a11, bs1B, cb);
            const int tp  = mt >> 1;
            const int off = (mt & 1) * 4;
#pragma unroll
            for (int i = 0; i < 4; ++i) {
                h10a[tp][off + i] = (_Float16)fmaxf(acc0A[i], 0.f);
                h10b[tp][off + i] = (_Float16)fmaxf(acc0B[i], 0.f);
                h11a[tp][off + i] = (_Float16)fmaxf(acc1A[i], 0.f);
                h11b[tp][off + i] = (_Float16)fmaxf(acc1B[i], 0.f);
            }
        }

        // GEMM2' + head interleaved; a2l fragments shared across both sgs
        f32x4 acc3_0a = c3init, acc3_0b = c3init;
        f32x4 acc3_1a = c3init, acc3_1b = c3init;
        __builtin_amdgcn_s_setprio(1);
#pragma unroll
        for (int mo = 0; mo < 8; ++mo) {
            const f32x4 cb = *(const f32x4*)(b2l + mo * 16 + quad * 4);
            f32x4 a0a = cb, a0b = cb, a1a = cb, a1b = cb;
#pragma unroll
            for (int tp = 0; tp < 4; ++tp) {
                const half8 w = a2l[(mo * 4 + tp) * 64 + lane];
                a0a = MFMA32(w, h10a[tp], a0a);
                a0b = MFMA32(w, h10b[tp], a0b);
                a1a = MFMA32(w, h11a[tp], a1a);
                a1b = MFMA32(w, h11b[tp], a1b);
            }
            half4 h20a, h20b, h21a, h21b;
#pragma unroll
            for (int i = 0; i < 4; ++i) {
                h20a[i] = (_Float16)fmaxf(a0a[i], 0.f);
                h20b[i] = (_Float16)fmaxf(a0b[i], 0.f);
                h21a[i] = (_Float16)fmaxf(a1a[i], 0.f);
                h21b[i] = (_Float16)fmaxf(a1b[i], 0.f);
            }
            const half4 w3 = a3l[mo * 64 + lane];
            acc3_0a = MFMA16(w3, h20a, acc3_0a);
            acc3_0b = MFMA16(w3, h20b, acc3_0b);
            acc3_1a = MFMA16(w3, h21a, acc3_1a);
            acc3_1b = MFMA16(w3, h21b, acc3_1b);
        }
        __builtin_amdgcn_s_setprio(0);

        if (quad == 0) {
            if (act0 && (base0 + n16 < ge0)) {
                f32x4 o;
                o[0] = fast_tanh(acc3_0a[0]); o[1] = fast_tanh(acc3_0a[1]);
                o[2] = acc3_0a[2];            o[3] = acc3_0a[3];
                *(f32x4*)(out + (base0 + n16) * 4) = o;
            }
            if (act0 && (base0 + 16 + n16 < ge0)) {
                f32x4 o;
                o[0] = fast_tanh(acc3_0b[0]); o[1] = fast_tanh(acc3_0b[1]);
                o[2] = acc3_0b[2];            o[3] = acc3_0b[3];
                *(f32x4*)(out + (base0 + 16 + n16) * 4) = o;
            }
            if (act1 && (base1 + n16 < ge1)) {
                f32x4 o;
                o[0] = fast_tanh(acc3_1a[0]); o[1] = fast_tanh(acc3_1a[1]);
                o[2] = acc3_1a[2];            o[3] = acc3_1a[3];
                *(f32x4*)(out + (base1 + n16) * 4) = o;
            }
            if (act1 && (base1 + 16 + n16 < ge1)) {
                f32x4 o;
                o[0] = fast_tanh(acc3_1b[0]); o[1] = fast_tanh(acc3_1b[1]);
                o[2] = acc3_1b[2];            o[3] = acc3_1b[3];
                *(f32x4*)(out + (base1 + 16 + n16) * 4) = o;
            }
        }
    }

    // safety net if grid ever shrinks below 1024 (zero iterations at grid=1024)
    for (int sgi = wid + 2 * nw; sgi < TOTAL_SG; sgi += nw) {
        const int g    = sgi >> 7;
        const int gs   = gstart[g];
        const int ge   = gstart[g + 1];
        const int base = gs + (sgi & 127) * 32;
        if (base >= ge) continue;
        f32x4 sa, sb;
        load_s(s, base, ge, n16, quad, sa, sb);
        compute_sg(g, base, ge, cvt4(sa), cvt4(sb),
                   zwt, a2l, a3l, b1l, b2l, c3init, out, lane, n16, quad);
    }
}

extern "C" void kernel_launch(void* const* d_in, const int* in_sizes, int n_in,
                              void* d_out, int out_size, void* d_ws, size_t ws_size,
                              hipStream_t stream)
{
    const float* z     = (const float*)d_in[0];
    const float* s     = (const float*)d_in[1];
    const int*   batch = (const int*)d_in[2];
    const float* W1    = (const float*)d_in[3];
    const float* b1    = (const float*)d_in[4];
    const float* W2    = (const float*)d_in[5];
    const float* b2    = (const float*)d_in[6];
    const float* Wp    = (const float*)d_in[7];
    const float* bp    = (const float*)d_in[8];
    const float* Wv    = (const float*)d_in[9];
    const float* bv    = (const float*)d_in[10];
    float* out = (float*)d_out;

    char* w = (char*)d_ws;
    _Float16* zwt = (_Float16*)(w + WS_ZWT);
    int* gstart   = (int*)(w + WS_GSTART);
    char* img     = w + WS_IMG;

    hipLaunchKernelGGL(gnn_prep, dim3(1305), dim3(256), 0, stream,
                       batch, z, W1, W2, Wp, Wv, b1, b2, gstart, zwt, img);
    hipLaunchKernelGGL(gnn_main, dim3(1024), dim3(256), 0, stream,
                       s, bp, bv, zwt, img, gstart, out);
}